// Round 5
// baseline (288.531 us; speedup 1.0000x reference)
//
#include <hip/hip_runtime.h>

typedef float vf4 __attribute__((ext_vector_type(4)));

__device__ __forceinline__ float4 ntload4(const float4* p) {
    vf4 v = __builtin_nontemporal_load((const vf4*)p);
    float4 r; r.x = v.x; r.y = v.y; r.z = v.z; r.w = v.w;
    return r;
}

__device__ __forceinline__ float4 exp4(float4 v) {
    float4 r;
    r.x = __expf(v.x); r.y = __expf(v.y); r.z = __expf(v.z); r.w = __expf(v.w);
    return r;
}

__device__ __forceinline__ void acc4(float4& a, float4 e) {
    a.x += e.x; a.y += e.y; a.z += e.z; a.w += e.w;
}

__device__ __forceinline__ float wave_reduce(float v) {
    #pragma unroll
    for (int off = 32; off > 0; off >>= 1) v += __shfl_down(v, off, 64);
    return v;
}

// ================= PREP: build group->rows CSR (counts pre-zeroed by memset) ================
// grid = 8, block = 1024
__global__ __launch_bounds__(1024) void PREP(const int* __restrict__ idx,
                                             int* __restrict__ counts,
                                             int* __restrict__ rowlist) {
    const int j = blockIdx.x * 1024 + threadIdx.x;   // 0..8191
    const int g = idx[j];
    const int p = atomicAdd(&counts[g], 1);
    if (p < 64) rowlist[(g << 6) + p] = j;
}

// ================= MEGA: blocks 0..255 theta1 path; blocks 256..4351 theta0 (g,chunk) ======
// block = 256. Seg path is BARRIER-FREE: metadata via wave-uniform scalar loads,
// each of the 4 waves runs an independent 8-deep nt-load gather pipeline.
__global__ __launch_bounds__(256) void MEGA(const float4* __restrict__ theta0,
                                            const float4* __restrict__ obs0,
                                            const int* __restrict__ idx,
                                            const float4* __restrict__ theta1,
                                            const float4* __restrict__ mapping1,
                                            float4* __restrict__ s0,     // nullptr => p2fb atomics
                                            float* __restrict__ p2fb,
                                            float* __restrict__ lossApart, // [64] spread partials
                                            float* __restrict__ m1part,  // [8][512]
                                            const int* __restrict__ counts,   // may be null
                                            const int* __restrict__ rowlist)  // may be null
{
    __shared__ float p1s[16];

    const int t = threadIdx.x, lane = t & 63, wave = t >> 6;

    if (blockIdx.x < 256) {
        // ---- theta1: 16 row-sums of exp (nt loads), then mapping1 slice -> m1part ----
        const int b2 = blockIdx.x;
        #pragma unroll
        for (int rr = 0; rr < 4; ++rr) {
            const int lr = wave * 4 + rr;        // 0..15
            const float4* rp = theta1 + (size_t)(b2 * 16 + lr) * 512;
            float a = 0.f;
            #pragma unroll
            for (int i = 0; i < 8; ++i) {
                const float4 x = ntload4(rp + lane + i * 64);
                a += __expf(x.x) + __expf(x.y) + __expf(x.z) + __expf(x.w);
            }
            a = wave_reduce(a);
            if (lane == 0) p1s[lr] = a;
        }
        __syncthreads();
        float* mdst = m1part + (b2 & 7) * 512;
        #pragma unroll
        for (int rr = 0; rr < 2; ++rr) {
            const int r = t * 2 + rr;            // 0..511
            const float4* mp = mapping1 + (size_t)r * 1024 + b2 * 4;
            float s = 0.f;
            #pragma unroll
            for (int j = 0; j < 4; ++j) {
                const float4 m = ntload4(mp + j);
                s += m.x * p1s[j*4+0] + m.y * p1s[j*4+1]
                   + m.z * p1s[j*4+2] + m.w * p1s[j*4+3];
            }
            atomicAdd(&mdst[r], s);
        }
        return;
    }

    // ---- theta0 segment path: block (g, chunk), no barriers, no LDS ----
    const int bb = blockIdx.x - 256;
    const int g  = bb & 1023;
    const int c  = bb >> 10;

    const float4* base = theta0 + (size_t)c * 256 + t;
    const size_t  o    = (size_t)g * 1024 + (size_t)c * 256 + t;
    const float4  ob   = ntload4(obs0 + o);     // independent, issued early

    float4 acc0 = {0,0,0,0}, acc1 = {0,0,0,0};

    if (counts) {
        const int n = counts[g];                 // wave-uniform scalar load
        if (n <= 64) {
            const int* rl = rowlist + (g << 6);  // 64 entries always allocated
            // wave-uniform row ids -> SGPRs; 8-deep two-bank load pipeline
            const int r0 = rl[0],  r1 = rl[1],  r2 = rl[2],  r3 = rl[3];
            const int r4 = rl[4],  r5 = rl[5],  r6 = rl[6],  r7 = rl[7];
            const int r8 = rl[8],  r9 = rl[9],  r10 = rl[10], r11 = rl[11];
            const int r12 = rl[12], r13 = rl[13], r14 = rl[14], r15 = rl[15];

            float4 A0, A1, A2, A3, B0, B1, B2, B3;
            if (n > 0)  A0 = ntload4(base + (size_t)r0  * 1024);
            if (n > 1)  A1 = ntload4(base + (size_t)r1  * 1024);
            if (n > 2)  A2 = ntload4(base + (size_t)r2  * 1024);
            if (n > 3)  A3 = ntload4(base + (size_t)r3  * 1024);
            if (n > 4)  B0 = ntload4(base + (size_t)r4  * 1024);
            if (n > 5)  B1 = ntload4(base + (size_t)r5  * 1024);
            if (n > 6)  B2 = ntload4(base + (size_t)r6  * 1024);
            if (n > 7)  B3 = ntload4(base + (size_t)r7  * 1024);

            if (n > 0)  acc4(acc0, exp4(A0));
            if (n > 1)  acc4(acc1, exp4(A1));
            if (n > 2)  acc4(acc0, exp4(A2));
            if (n > 3)  acc4(acc1, exp4(A3));
            if (n > 8)  A0 = ntload4(base + (size_t)r8  * 1024);
            if (n > 9)  A1 = ntload4(base + (size_t)r9  * 1024);
            if (n > 10) A2 = ntload4(base + (size_t)r10 * 1024);
            if (n > 11) A3 = ntload4(base + (size_t)r11 * 1024);

            if (n > 4)  acc4(acc0, exp4(B0));
            if (n > 5)  acc4(acc1, exp4(B1));
            if (n > 6)  acc4(acc0, exp4(B2));
            if (n > 7)  acc4(acc1, exp4(B3));
            if (n > 12) B0 = ntload4(base + (size_t)r12 * 1024);
            if (n > 13) B1 = ntload4(base + (size_t)r13 * 1024);
            if (n > 14) B2 = ntload4(base + (size_t)r14 * 1024);
            if (n > 15) B3 = ntload4(base + (size_t)r15 * 1024);

            if (n > 8)  acc4(acc0, exp4(A0));
            if (n > 9)  acc4(acc1, exp4(A1));
            if (n > 10) acc4(acc0, exp4(A2));
            if (n > 11) acc4(acc1, exp4(A3));
            if (n > 12) acc4(acc0, exp4(B0));
            if (n > 13) acc4(acc1, exp4(B1));
            if (n > 14) acc4(acc0, exp4(B2));
            if (n > 15) acc4(acc1, exp4(B3));

            // rare tail (16 < n <= 64), uniform scalar row ids
            for (int s = 16; s < n; ++s)
                acc4(acc0, exp4(ntload4(base + (size_t)rl[s] * 1024)));
        } else {
            // CSR overflow (n > 64): uniform scan-gather, barrier-free
            for (int j = 0; j < 8192; ++j)
                if (idx[j] == g) acc4(acc0, exp4(ntload4(base + (size_t)j * 1024)));
        }
    } else {
        // no-CSR fallback: uniform scan-gather, barrier-free (correctness path)
        for (int j = 0; j < 8192; ++j)
            if (idx[j] == g) acc4(acc0, exp4(ntload4(base + (size_t)j * 1024)));
    }

    float4 sv;
    sv.x = acc0.x + acc1.x; sv.y = acc0.y + acc1.y;
    sv.z = acc0.z + acc1.z; sv.w = acc0.w + acc1.w;

    if (s0) {
        s0[o] = sv;
    } else {
        const int cc = c * 1024 + t * 4;
        atomicAdd(&p2fb[cc + 0], sv.x);
        atomicAdd(&p2fb[cc + 1], sv.y);
        atomicAdd(&p2fb[cc + 2], sv.z);
        atomicAdd(&p2fb[cc + 3], sv.w);
    }

    const float dx = ob.x - sv.x, dy = ob.y - sv.y, dz = ob.z - sv.z, dw = ob.w - sv.w;
    float l = dx*dx + dy*dy + dz*dz + dw*dw;
    l = wave_reduce(l);
    if (lane == 0) atomicAdd(&lossApart[bb & 63], l);   // spread: no same-address pileup
}

// ================= K3F: column sums of s0 + loss_c; last block does loss_b + combine =========
// grid = 64, block = 1024
__global__ __launch_bounds__(1024) void K3F(const float* __restrict__ s0,
                                            const float* __restrict__ obs2,
                                            const float* __restrict__ lossApart,
                                            float* __restrict__ lossC,
                                            int* __restrict__ ticket,
                                            const float* __restrict__ m1part,
                                            const float* __restrict__ obs1,
                                            float* __restrict__ out) {
    __shared__ float part[16][64];
    __shared__ int isLast;
    const int tid = threadIdx.x, lane = tid & 63, wave = tid >> 6;
    const int col = blockIdx.x * 64 + lane;
    const float* p = s0 + (size_t)wave * 4096 + col;
    float a = 0.f;
    #pragma unroll 4
    for (int g = 0; g < 64; ++g) a += p[(size_t)g * 16 * 4096];
    part[wave][lane] = a;
    __syncthreads();
    if (wave == 0) {
        float s = 0.f;
        #pragma unroll
        for (int k = 0; k < 16; ++k) s += part[k][lane];
        const float d = obs2[col] - s;
        const float l = wave_reduce(d * d);
        if (lane == 0) {
            atomicAdd(lossC, l);
            __threadfence();
        }
    }
    __syncthreads();
    if (tid == 0) isLast = (atomicAdd(ticket, 1) == 63) ? 1 : 0;
    __syncthreads();
    if (!isLast) return;

    // ---- final: loss_b + lossA partials + combine ----
    __shared__ float wb[16];
    __shared__ float la_s;
    float lb = 0.f;
    if (tid < 512) {
        float m = 0.f;
        #pragma unroll
        for (int k = 0; k < 8; ++k) m += m1part[k * 512 + tid];
        const float d = obs1[tid] - m;
        lb = d * d;
    }
    lb = wave_reduce(lb);
    if (lane == 0) wb[wave] = lb;
    if (wave == 0) {
        float la = (lane < 64) ? lossApart[lane] : 0.f;
        la = wave_reduce(la);
        if (lane == 0) la_s = la;
    }
    __syncthreads();
    if (tid == 0) {
        float sb = 0.f;
        #pragma unroll
        for (int i = 0; i < 16; ++i) sb += wb[i];
        const float sc = atomicAdd(lossC, 0.f);   // coherent read
        const float la = la_s / 4194304.f;
        out[0] = (la + sb / 512.f + 0.5f * sc / 4096.f) / 3.f;
    }
}

// ================= FINFB: fallback final (loss_b + loss_c from p2fb + combine) ==============
// grid = 1, block = 512
__global__ __launch_bounds__(512) void FINFB(const float* __restrict__ m1part,
                                             const float* __restrict__ obs1,
                                             const float* __restrict__ lossApart,
                                             const float* __restrict__ p2,
                                             const float* __restrict__ obs2,
                                             float* __restrict__ out) {
    __shared__ float wb[8];
    __shared__ float wc[8];
    __shared__ float la_s;
    const int t = threadIdx.x, lane = t & 63, wave = t >> 6;
    float m = 0.f;
    #pragma unroll
    for (int k = 0; k < 8; ++k) m += m1part[k * 512 + t];
    const float d = obs1[t] - m;
    const float lb = wave_reduce(d * d);
    float acc = 0.f;
    #pragma unroll
    for (int i = 0; i < 8; ++i) {
        const int c = t + i * 512;
        const float dd = obs2[c] - p2[c];
        acc += dd * dd;
    }
    const float lc = wave_reduce(acc);
    if (lane == 0) { wb[wave] = lb; wc[wave] = lc; }
    if (wave == 0) {
        float la = (lane < 64) ? lossApart[lane] : 0.f;
        la = wave_reduce(la);
        if (lane == 0) la_s = la;
    }
    __syncthreads();
    if (t == 0) {
        float sb = 0.f, sc = 0.f;
        #pragma unroll
        for (int i = 0; i < 8; ++i) { sb += wb[i]; sc += wc[i]; }
        const float la = la_s / 4194304.f;
        out[0] = (la + sb / 512.f + 0.5f * sc / 4096.f) / 3.f;
    }
}

extern "C" void kernel_launch(void* const* d_in, const int* in_sizes, int n_in,
                              void* d_out, int out_size, void* d_ws, size_t ws_size,
                              hipStream_t stream) {
    const float* theta0   = (const float*)d_in[0];   // [8192,4096]
    const float* theta1   = (const float*)d_in[1];   // [4096,2048]
    const float* obs0     = (const float*)d_in[2];   // [1024,4096]
    const float* obs1     = (const float*)d_in[3];   // [512]
    const float* obs2     = (const float*)d_in[4];   // [4096]
    const int*   idx0     = (const int*)d_in[5];     // [8192]
    const float* mapping1 = (const float*)d_in[6];   // [512,4096]
    float* out = (float*)d_out;

    char* ws = (char*)d_ws;
    float* lossC    = (float*)(ws + 0);        // 1 float
    int*   ticket   = (int*)(ws + 16);
    float* lossApart= (float*)(ws + 64);       // 64 floats, ends 320
    float* m1part   = (float*)(ws + 1024);     // 8*512 floats, ends 17408
    int*   counts   = (int*)(ws + 17408);      // 1024 ints, ends 21504
    float* p2fb     = (float*)(ws + 21504);    // 4096 floats, ends 37888
    float* s0       = (float*)(ws + 65536);    // 16 MB, ends 16842752
    int*   rowlist  = (int*)(ws + 16842752);   // 1024*64 ints, ends 17104896

    const size_t NEED_S0  = 16842752;
    const size_t NEED_ALL = 17104896;
    const bool haveS0  = ws_size >= NEED_S0;
    const bool haveCSR = ws_size >= NEED_ALL;

    hipMemsetAsync(ws, 0, 37888, stream);  // lossC + ticket + lossApart + m1part + counts + p2fb

    if (haveCSR) PREP<<<8, 1024, 0, stream>>>(idx0, counts, rowlist);

    MEGA<<<4352, 256, 0, stream>>>((const float4*)theta0, (const float4*)obs0, idx0,
                                   (const float4*)theta1, (const float4*)mapping1,
                                   haveS0 ? (float4*)s0 : nullptr, p2fb,
                                   lossApart, m1part,
                                   haveCSR ? counts : nullptr,
                                   haveCSR ? rowlist : nullptr);

    if (haveS0) {
        K3F<<<64, 1024, 0, stream>>>(s0, obs2, lossApart, lossC, ticket,
                                     m1part, obs1, out);
    } else {
        FINFB<<<1, 512, 0, stream>>>(m1part, obs1, lossApart, p2fb, obs2, out);
    }
}

// Round 6
// 262.114 us; speedup vs baseline: 1.1008x; 1.1008x over previous
//
#include <hip/hip_runtime.h>

typedef float vf4 __attribute__((ext_vector_type(4)));

__device__ __forceinline__ float4 ntload4(const float4* p) {
    vf4 v = __builtin_nontemporal_load((const vf4*)p);
    float4 r; r.x = v.x; r.y = v.y; r.z = v.z; r.w = v.w;
    return r;
}

__device__ __forceinline__ float4 exp4(float4 v) {
    float4 r;
    r.x = __expf(v.x); r.y = __expf(v.y); r.z = __expf(v.z); r.w = __expf(v.w);
    return r;
}

__device__ __forceinline__ void acc4(float4& a, float4 e) {
    a.x += e.x; a.y += e.y; a.z += e.z; a.w += e.w;
}

__device__ __forceinline__ float wave_reduce(float v) {
    #pragma unroll
    for (int off = 32; off > 0; off >>= 1) v += __shfl_down(v, off, 64);
    return v;
}

// ================= PREP: build group->rows CSR (counts pre-zeroed by memset) ================
// grid = 8, block = 1024
__global__ __launch_bounds__(1024) void PREP(const int* __restrict__ idx,
                                             int* __restrict__ counts,
                                             int* __restrict__ rowlist) {
    const int j = blockIdx.x * 1024 + threadIdx.x;   // 0..8191
    const int g = idx[j];
    const int p = atomicAdd(&counts[g], 1);
    if (p < 64) rowlist[(g << 6) + p] = j;
}

// ================= MEGA: blocks 0..255 theta1 path; blocks 256..2303 theta0 (g, chunk-pair) =
// block = 256. Seg path: LDS rowlist (parallel fetch + 1 barrier), then a continuous
// 4-row x 2-chunk unrolled gather (8 nt loads in flight per thread).
__global__ __launch_bounds__(256) void MEGA(const float4* __restrict__ theta0,
                                            const float4* __restrict__ obs0,
                                            const int* __restrict__ idx,
                                            const float4* __restrict__ theta1,
                                            const float4* __restrict__ mapping1,
                                            float4* __restrict__ s0,     // nullptr => p2fb atomics
                                            float* __restrict__ p2fb,
                                            float* __restrict__ lossApart, // [64] spread partials
                                            float* __restrict__ m1part,  // [8][512]
                                            const int* __restrict__ counts,   // may be null
                                            const int* __restrict__ rowlist)  // may be null
{
    __shared__ int rows_lds[64];
    __shared__ float p1s[16];

    const int t = threadIdx.x, lane = t & 63, wave = t >> 6;

    if (blockIdx.x < 256) {
        // ---- theta1: 16 row-sums of exp (nt loads), then mapping1 slice -> m1part ----
        const int b2 = blockIdx.x;
        #pragma unroll
        for (int rr = 0; rr < 4; ++rr) {
            const int lr = wave * 4 + rr;        // 0..15
            const float4* rp = theta1 + (size_t)(b2 * 16 + lr) * 512;
            float a = 0.f;
            #pragma unroll
            for (int i = 0; i < 8; ++i) {
                const float4 x = ntload4(rp + lane + i * 64);
                a += __expf(x.x) + __expf(x.y) + __expf(x.z) + __expf(x.w);
            }
            a = wave_reduce(a);
            if (lane == 0) p1s[lr] = a;
        }
        __syncthreads();
        float* mdst = m1part + (b2 & 7) * 512;
        #pragma unroll
        for (int rr = 0; rr < 2; ++rr) {
            const int r = t * 2 + rr;            // 0..511
            const float4* mp = mapping1 + (size_t)r * 1024 + b2 * 4;
            float s = 0.f;
            #pragma unroll
            for (int j = 0; j < 4; ++j) {
                const float4 m = ntload4(mp + j);
                s += m.x * p1s[j*4+0] + m.y * p1s[j*4+1]
                   + m.z * p1s[j*4+2] + m.w * p1s[j*4+3];
            }
            atomicAdd(&mdst[r], s);
        }
        return;
    }

    // ---- theta0 segment path: block (g, chunk-pair) ----
    const int bb  = blockIdx.x - 256;
    const int g   = bb & 1023;
    const int pr  = bb >> 10;              // 0 or 1
    const int col = pr * 512 + t;          // float4 index in row, covers col and col+256

    const float4* base = theta0 + col;
    const size_t  o0   = (size_t)g * 1024 + col;
    const size_t  o1   = o0 + 256;
    const float4  obA  = ntload4(obs0 + o0);   // independent, issued early
    const float4  obB  = ntload4(obs0 + o1);

    float4 aA = {0,0,0,0}, aB = {0,0,0,0};

    if (counts) {
        const int n = counts[g];                 // block-uniform
        if (n <= 64) {
            if (t < 64) rows_lds[t] = rowlist[(g << 6) + t];
            __syncthreads();
            int s = 0;
            for (; s + 4 <= n; s += 4) {
                const int r0 = rows_lds[s],     r1 = rows_lds[s + 1];
                const int r2 = rows_lds[s + 2], r3 = rows_lds[s + 3];
                const float4* p0 = base + (size_t)r0 * 1024;
                const float4* p1 = base + (size_t)r1 * 1024;
                const float4* p2 = base + (size_t)r2 * 1024;
                const float4* p3 = base + (size_t)r3 * 1024;
                const float4 A0 = ntload4(p0), A1 = ntload4(p0 + 256);
                const float4 B0 = ntload4(p1), B1 = ntload4(p1 + 256);
                const float4 C0 = ntload4(p2), C1 = ntload4(p2 + 256);
                const float4 D0 = ntload4(p3), D1 = ntload4(p3 + 256);
                acc4(aA, exp4(A0)); acc4(aB, exp4(A1));
                acc4(aA, exp4(B0)); acc4(aB, exp4(B1));
                acc4(aA, exp4(C0)); acc4(aB, exp4(C1));
                acc4(aA, exp4(D0)); acc4(aB, exp4(D1));
            }
            for (; s < n; ++s) {
                const float4* p = base + (size_t)rows_lds[s] * 1024;
                const float4 X0 = ntload4(p), X1 = ntload4(p + 256);
                acc4(aA, exp4(X0)); acc4(aB, exp4(X1));
            }
        } else {
            // CSR overflow (n > 64): uniform scan-gather
            for (int j = 0; j < 8192; ++j)
                if (idx[j] == g) {
                    const float4* p = base + (size_t)j * 1024;
                    acc4(aA, exp4(ntload4(p)));
                    acc4(aB, exp4(ntload4(p + 256)));
                }
        }
    } else {
        // no-CSR fallback: uniform scan-gather (correctness path)
        for (int j = 0; j < 8192; ++j)
            if (idx[j] == g) {
                const float4* p = base + (size_t)j * 1024;
                acc4(aA, exp4(ntload4(p)));
                acc4(aB, exp4(ntload4(p + 256)));
            }
    }

    if (s0) {
        s0[o0] = aA;
        s0[o1] = aB;
    } else {
        const int cc0 = col * 4;
        const int cc1 = cc0 + 1024;
        atomicAdd(&p2fb[cc0 + 0], aA.x); atomicAdd(&p2fb[cc0 + 1], aA.y);
        atomicAdd(&p2fb[cc0 + 2], aA.z); atomicAdd(&p2fb[cc0 + 3], aA.w);
        atomicAdd(&p2fb[cc1 + 0], aB.x); atomicAdd(&p2fb[cc1 + 1], aB.y);
        atomicAdd(&p2fb[cc1 + 2], aB.z); atomicAdd(&p2fb[cc1 + 3], aB.w);
    }

    const float dx0 = obA.x - aA.x, dy0 = obA.y - aA.y, dz0 = obA.z - aA.z, dw0 = obA.w - aA.w;
    const float dx1 = obB.x - aB.x, dy1 = obB.y - aB.y, dz1 = obB.z - aB.z, dw1 = obB.w - aB.w;
    float l = dx0*dx0 + dy0*dy0 + dz0*dz0 + dw0*dw0
            + dx1*dx1 + dy1*dy1 + dz1*dz1 + dw1*dw1;
    l = wave_reduce(l);
    if (lane == 0) atomicAdd(&lossApart[bb & 63], l);   // spread partials
}

// ================= K3F: column sums of s0 + loss_c; last block does loss_b + combine =========
// grid = 64, block = 1024
__global__ __launch_bounds__(1024) void K3F(const float* __restrict__ s0,
                                            const float* __restrict__ obs2,
                                            const float* __restrict__ lossApart,
                                            float* __restrict__ lossC,
                                            int* __restrict__ ticket,
                                            const float* __restrict__ m1part,
                                            const float* __restrict__ obs1,
                                            float* __restrict__ out) {
    __shared__ float part[16][64];
    __shared__ int isLast;
    const int tid = threadIdx.x, lane = tid & 63, wave = tid >> 6;
    const int col = blockIdx.x * 64 + lane;
    const float* p = s0 + (size_t)wave * 4096 + col;
    float a = 0.f;
    #pragma unroll 4
    for (int g = 0; g < 64; ++g) a += p[(size_t)g * 16 * 4096];
    part[wave][lane] = a;
    __syncthreads();
    if (wave == 0) {
        float s = 0.f;
        #pragma unroll
        for (int k = 0; k < 16; ++k) s += part[k][lane];
        const float d = obs2[col] - s;
        const float l = wave_reduce(d * d);
        if (lane == 0) {
            atomicAdd(lossC, l);
            __threadfence();
        }
    }
    __syncthreads();
    if (tid == 0) isLast = (atomicAdd(ticket, 1) == 63) ? 1 : 0;
    __syncthreads();
    if (!isLast) return;

    // ---- final: loss_b + lossA partials + combine ----
    __shared__ float wb[16];
    __shared__ float la_s;
    float lb = 0.f;
    if (tid < 512) {
        float m = 0.f;
        #pragma unroll
        for (int k = 0; k < 8; ++k) m += m1part[k * 512 + tid];
        const float d = obs1[tid] - m;
        lb = d * d;
    }
    lb = wave_reduce(lb);
    if (lane == 0) wb[wave] = lb;
    if (wave == 0) {
        float la = (lane < 64) ? lossApart[lane] : 0.f;
        la = wave_reduce(la);
        if (lane == 0) la_s = la;
    }
    __syncthreads();
    if (tid == 0) {
        float sb = 0.f;
        #pragma unroll
        for (int i = 0; i < 16; ++i) sb += wb[i];
        const float sc = atomicAdd(lossC, 0.f);   // coherent read
        const float la = la_s / 4194304.f;
        out[0] = (la + sb / 512.f + 0.5f * sc / 4096.f) / 3.f;
    }
}

// ================= FINFB: fallback final (loss_b + loss_c from p2fb + combine) ==============
// grid = 1, block = 512
__global__ __launch_bounds__(512) void FINFB(const float* __restrict__ m1part,
                                             const float* __restrict__ obs1,
                                             const float* __restrict__ lossApart,
                                             const float* __restrict__ p2,
                                             const float* __restrict__ obs2,
                                             float* __restrict__ out) {
    __shared__ float wb[8];
    __shared__ float wc[8];
    __shared__ float la_s;
    const int t = threadIdx.x, lane = t & 63, wave = t >> 6;
    float m = 0.f;
    #pragma unroll
    for (int k = 0; k < 8; ++k) m += m1part[k * 512 + t];
    const float d = obs1[t] - m;
    const float lb = wave_reduce(d * d);
    float acc = 0.f;
    #pragma unroll
    for (int i = 0; i < 8; ++i) {
        const int c = t + i * 512;
        const float dd = obs2[c] - p2[c];
        acc += dd * dd;
    }
    const float lc = wave_reduce(acc);
    if (lane == 0) { wb[wave] = lb; wc[wave] = lc; }
    if (wave == 0) {
        float la = (lane < 64) ? lossApart[lane] : 0.f;
        la = wave_reduce(la);
        if (lane == 0) la_s = la;
    }
    __syncthreads();
    if (t == 0) {
        float sb = 0.f, sc = 0.f;
        #pragma unroll
        for (int i = 0; i < 8; ++i) { sb += wb[i]; sc += wc[i]; }
        const float la = la_s / 4194304.f;
        out[0] = (la + sb / 512.f + 0.5f * sc / 4096.f) / 3.f;
    }
}

extern "C" void kernel_launch(void* const* d_in, const int* in_sizes, int n_in,
                              void* d_out, int out_size, void* d_ws, size_t ws_size,
                              hipStream_t stream) {
    const float* theta0   = (const float*)d_in[0];   // [8192,4096]
    const float* theta1   = (const float*)d_in[1];   // [4096,2048]
    const float* obs0     = (const float*)d_in[2];   // [1024,4096]
    const float* obs1     = (const float*)d_in[3];   // [512]
    const float* obs2     = (const float*)d_in[4];   // [4096]
    const int*   idx0     = (const int*)d_in[5];     // [8192]
    const float* mapping1 = (const float*)d_in[6];   // [512,4096]
    float* out = (float*)d_out;

    char* ws = (char*)d_ws;
    float* lossC    = (float*)(ws + 0);        // 1 float
    int*   ticket   = (int*)(ws + 16);
    float* lossApart= (float*)(ws + 64);       // 64 floats, ends 320
    float* m1part   = (float*)(ws + 1024);     // 8*512 floats, ends 17408
    int*   counts   = (int*)(ws + 17408);      // 1024 ints, ends 21504
    float* p2fb     = (float*)(ws + 21504);    // 4096 floats, ends 37888
    float* s0       = (float*)(ws + 65536);    // 16 MB, ends 16842752
    int*   rowlist  = (int*)(ws + 16842752);   // 1024*64 ints, ends 17104896

    const size_t NEED_S0  = 16842752;
    const size_t NEED_ALL = 17104896;
    const bool haveS0  = ws_size >= NEED_S0;
    const bool haveCSR = ws_size >= NEED_ALL;

    hipMemsetAsync(ws, 0, 37888, stream);  // lossC + ticket + lossApart + m1part + counts + p2fb

    if (haveCSR) PREP<<<8, 1024, 0, stream>>>(idx0, counts, rowlist);

    MEGA<<<2304, 256, 0, stream>>>((const float4*)theta0, (const float4*)obs0, idx0,
                                   (const float4*)theta1, (const float4*)mapping1,
                                   haveS0 ? (float4*)s0 : nullptr, p2fb,
                                   lossApart, m1part,
                                   haveCSR ? counts : nullptr,
                                   haveCSR ? rowlist : nullptr);

    if (haveS0) {
        K3F<<<64, 1024, 0, stream>>>(s0, obs2, lossApart, lossC, ticket,
                                     m1part, obs1, out);
    } else {
        FINFB<<<1, 512, 0, stream>>>(m1part, obs1, lossApart, p2fb, obs2, out);
    }
}

// Round 7
// 252.593 us; speedup vs baseline: 1.1423x; 1.0377x over previous
//
#include <hip/hip_runtime.h>

typedef float vf4 __attribute__((ext_vector_type(4)));

__device__ __forceinline__ float4 ntload4(const float4* p) {
    vf4 v = __builtin_nontemporal_load((const vf4*)p);
    float4 r; r.x = v.x; r.y = v.y; r.z = v.z; r.w = v.w;
    return r;
}

__device__ __forceinline__ float4 exp4(float4 v) {
    float4 r;
    r.x = __expf(v.x); r.y = __expf(v.y); r.z = __expf(v.z); r.w = __expf(v.w);
    return r;
}

__device__ __forceinline__ void acc4(float4& a, float4 e) {
    a.x += e.x; a.y += e.y; a.z += e.z; a.w += e.w;
}

__device__ __forceinline__ float wave_reduce(float v) {
    #pragma unroll
    for (int off = 32; off > 0; off >>= 1) v += __shfl_down(v, off, 64);
    return v;
}

// ================= PREP: build group->rows CSR (counts pre-zeroed by memset) ================
// grid = 8, block = 1024
__global__ __launch_bounds__(1024) void PREP(const int* __restrict__ idx,
                                             int* __restrict__ counts,
                                             int* __restrict__ rowlist) {
    const int j = blockIdx.x * 1024 + threadIdx.x;   // 0..8191
    const int g = idx[j];
    const int p = atomicAdd(&counts[g], 1);
    if (p < 64) rowlist[(g << 6) + p] = j;
}

// ================= MEGA: blocks 0..255 theta1 path; blocks 256..1279 theta0 full-row groups =
// block = 256. Seg path: one block per group g; each row read ONCE as 16 KB contiguous;
// 2-row x 4-chunk ladder keeps 8 nt loads in flight per thread.
__global__ __launch_bounds__(256) void MEGA(const float4* __restrict__ theta0,
                                            const float4* __restrict__ obs0,
                                            const int* __restrict__ idx,
                                            const float4* __restrict__ theta1,
                                            const float4* __restrict__ mapping1,
                                            float4* __restrict__ s0,     // nullptr => p2fb atomics
                                            float* __restrict__ p2fb,
                                            float* __restrict__ lossApart, // [64] spread partials
                                            float* __restrict__ m1part,  // [8][512]
                                            const int* __restrict__ counts,   // may be null
                                            const int* __restrict__ rowlist)  // may be null
{
    __shared__ int rows_lds[64];
    __shared__ float p1s[16];

    const int t = threadIdx.x, lane = t & 63, wave = t >> 6;

    if (blockIdx.x < 256) {
        // ---- theta1: 16 row-sums of exp (nt loads), then mapping1 slice -> m1part ----
        const int b2 = blockIdx.x;
        #pragma unroll
        for (int rr = 0; rr < 4; ++rr) {
            const int lr = wave * 4 + rr;        // 0..15
            const float4* rp = theta1 + (size_t)(b2 * 16 + lr) * 512;
            float a = 0.f;
            #pragma unroll
            for (int i = 0; i < 8; ++i) {
                const float4 x = ntload4(rp + lane + i * 64);
                a += __expf(x.x) + __expf(x.y) + __expf(x.z) + __expf(x.w);
            }
            a = wave_reduce(a);
            if (lane == 0) p1s[lr] = a;
        }
        __syncthreads();
        float* mdst = m1part + (b2 & 7) * 512;
        #pragma unroll
        for (int rr = 0; rr < 2; ++rr) {
            const int r = t * 2 + rr;            // 0..511
            const float4* mp = mapping1 + (size_t)r * 1024 + b2 * 4;
            float s = 0.f;
            #pragma unroll
            for (int j = 0; j < 4; ++j) {
                const float4 m = ntload4(mp + j);
                s += m.x * p1s[j*4+0] + m.y * p1s[j*4+1]
                   + m.z * p1s[j*4+2] + m.w * p1s[j*4+3];
            }
            atomicAdd(&mdst[r], s);
        }
        return;
    }

    // ---- theta0 segment path: one block per group, full 16 KB rows ----
    const int g = blockIdx.x - 256;

    const float4* base = theta0 + t;
    const size_t  o    = (size_t)g * 1024 + t;
    const float4  obA  = ntload4(obs0 + o);          // independent, issued early
    const float4  obB  = ntload4(obs0 + o + 256);
    const float4  obC  = ntload4(obs0 + o + 512);
    const float4  obD  = ntload4(obs0 + o + 768);

    float4 aA = {0,0,0,0}, aB = {0,0,0,0}, aC = {0,0,0,0}, aD = {0,0,0,0};

    if (counts) {
        const int n = counts[g];                 // block-uniform
        if (n <= 64) {
            if (t < 64) rows_lds[t] = rowlist[(g << 6) + t];
            __syncthreads();
            int s = 0;
            for (; s + 2 <= n; s += 2) {
                const float4* p0 = base + (size_t)rows_lds[s]     * 1024;
                const float4* p1 = base + (size_t)rows_lds[s + 1] * 1024;
                const float4 x0 = ntload4(p0),       x1 = ntload4(p0 + 256);
                const float4 x2 = ntload4(p0 + 512), x3 = ntload4(p0 + 768);
                const float4 y0 = ntload4(p1),       y1 = ntload4(p1 + 256);
                const float4 y2 = ntload4(p1 + 512), y3 = ntload4(p1 + 768);
                acc4(aA, exp4(x0)); acc4(aB, exp4(x1));
                acc4(aC, exp4(x2)); acc4(aD, exp4(x3));
                acc4(aA, exp4(y0)); acc4(aB, exp4(y1));
                acc4(aC, exp4(y2)); acc4(aD, exp4(y3));
            }
            if (s < n) {
                const float4* p0 = base + (size_t)rows_lds[s] * 1024;
                const float4 x0 = ntload4(p0),       x1 = ntload4(p0 + 256);
                const float4 x2 = ntload4(p0 + 512), x3 = ntload4(p0 + 768);
                acc4(aA, exp4(x0)); acc4(aB, exp4(x1));
                acc4(aC, exp4(x2)); acc4(aD, exp4(x3));
            }
        } else {
            // CSR overflow (n > 64): uniform scan-gather
            for (int j = 0; j < 8192; ++j)
                if (idx[j] == g) {
                    const float4* p = base + (size_t)j * 1024;
                    acc4(aA, exp4(ntload4(p)));
                    acc4(aB, exp4(ntload4(p + 256)));
                    acc4(aC, exp4(ntload4(p + 512)));
                    acc4(aD, exp4(ntload4(p + 768)));
                }
        }
    } else {
        // no-CSR fallback: uniform scan-gather (correctness path)
        for (int j = 0; j < 8192; ++j)
            if (idx[j] == g) {
                const float4* p = base + (size_t)j * 1024;
                acc4(aA, exp4(ntload4(p)));
                acc4(aB, exp4(ntload4(p + 256)));
                acc4(aC, exp4(ntload4(p + 512)));
                acc4(aD, exp4(ntload4(p + 768)));
            }
    }

    if (s0) {
        s0[o]       = aA;
        s0[o + 256] = aB;
        s0[o + 512] = aC;
        s0[o + 768] = aD;
    } else {
        #pragma unroll
        for (int k = 0; k < 4; ++k) {
            const float4 v = (k == 0) ? aA : (k == 1) ? aB : (k == 2) ? aC : aD;
            const int cc = (t + k * 256) * 4;
            atomicAdd(&p2fb[cc + 0], v.x); atomicAdd(&p2fb[cc + 1], v.y);
            atomicAdd(&p2fb[cc + 2], v.z); atomicAdd(&p2fb[cc + 3], v.w);
        }
    }

    const float dx0 = obA.x - aA.x, dy0 = obA.y - aA.y, dz0 = obA.z - aA.z, dw0 = obA.w - aA.w;
    const float dx1 = obB.x - aB.x, dy1 = obB.y - aB.y, dz1 = obB.z - aB.z, dw1 = obB.w - aB.w;
    const float dx2 = obC.x - aC.x, dy2 = obC.y - aC.y, dz2 = obC.z - aC.z, dw2 = obC.w - aC.w;
    const float dx3 = obD.x - aD.x, dy3 = obD.y - aD.y, dz3 = obD.z - aD.z, dw3 = obD.w - aD.w;
    float l = dx0*dx0 + dy0*dy0 + dz0*dz0 + dw0*dw0
            + dx1*dx1 + dy1*dy1 + dz1*dz1 + dw1*dw1
            + dx2*dx2 + dy2*dy2 + dz2*dz2 + dw2*dw2
            + dx3*dx3 + dy3*dy3 + dz3*dz3 + dw3*dw3;
    l = wave_reduce(l);
    if (lane == 0) atomicAdd(&lossApart[g & 63], l);   // spread partials
}

// ================= K3F: column sums of s0 + loss_c; last block does loss_b + combine =========
// grid = 64, block = 1024
__global__ __launch_bounds__(1024) void K3F(const float* __restrict__ s0,
                                            const float* __restrict__ obs2,
                                            const float* __restrict__ lossApart,
                                            float* __restrict__ lossC,
                                            int* __restrict__ ticket,
                                            const float* __restrict__ m1part,
                                            const float* __restrict__ obs1,
                                            float* __restrict__ out) {
    __shared__ float part[16][64];
    __shared__ int isLast;
    const int tid = threadIdx.x, lane = tid & 63, wave = tid >> 6;
    const int col = blockIdx.x * 64 + lane;
    const float* p = s0 + (size_t)wave * 4096 + col;
    float a = 0.f;
    #pragma unroll 4
    for (int g = 0; g < 64; ++g) a += p[(size_t)g * 16 * 4096];
    part[wave][lane] = a;
    __syncthreads();
    if (wave == 0) {
        float s = 0.f;
        #pragma unroll
        for (int k = 0; k < 16; ++k) s += part[k][lane];
        const float d = obs2[col] - s;
        const float l = wave_reduce(d * d);
        if (lane == 0) {
            atomicAdd(lossC, l);
            __threadfence();
        }
    }
    __syncthreads();
    if (tid == 0) isLast = (atomicAdd(ticket, 1) == 63) ? 1 : 0;
    __syncthreads();
    if (!isLast) return;

    // ---- final: loss_b + lossA partials + combine ----
    __shared__ float wb[16];
    __shared__ float la_s;
    float lb = 0.f;
    if (tid < 512) {
        float m = 0.f;
        #pragma unroll
        for (int k = 0; k < 8; ++k) m += m1part[k * 512 + tid];
        const float d = obs1[tid] - m;
        lb = d * d;
    }
    lb = wave_reduce(lb);
    if (lane == 0) wb[wave] = lb;
    if (wave == 0) {
        float la = (lane < 64) ? lossApart[lane] : 0.f;
        la = wave_reduce(la);
        if (lane == 0) la_s = la;
    }
    __syncthreads();
    if (tid == 0) {
        float sb = 0.f;
        #pragma unroll
        for (int i = 0; i < 16; ++i) sb += wb[i];
        const float sc = atomicAdd(lossC, 0.f);   // coherent read
        const float la = la_s / 4194304.f;
        out[0] = (la + sb / 512.f + 0.5f * sc / 4096.f) / 3.f;
    }
}

// ================= FINFB: fallback final (loss_b + loss_c from p2fb + combine) ==============
// grid = 1, block = 512
__global__ __launch_bounds__(512) void FINFB(const float* __restrict__ m1part,
                                             const float* __restrict__ obs1,
                                             const float* __restrict__ lossApart,
                                             const float* __restrict__ p2,
                                             const float* __restrict__ obs2,
                                             float* __restrict__ out) {
    __shared__ float wb[8];
    __shared__ float wc[8];
    __shared__ float la_s;
    const int t = threadIdx.x, lane = t & 63, wave = t >> 6;
    float m = 0.f;
    #pragma unroll
    for (int k = 0; k < 8; ++k) m += m1part[k * 512 + t];
    const float d = obs1[t] - m;
    const float lb = wave_reduce(d * d);
    float acc = 0.f;
    #pragma unroll
    for (int i = 0; i < 8; ++i) {
        const int c = t + i * 512;
        const float dd = obs2[c] - p2[c];
        acc += dd * dd;
    }
    const float lc = wave_reduce(acc);
    if (lane == 0) { wb[wave] = lb; wc[wave] = lc; }
    if (wave == 0) {
        float la = (lane < 64) ? lossApart[lane] : 0.f;
        la = wave_reduce(la);
        if (lane == 0) la_s = la;
    }
    __syncthreads();
    if (t == 0) {
        float sb = 0.f, sc = 0.f;
        #pragma unroll
        for (int i = 0; i < 8; ++i) { sb += wb[i]; sc += wc[i]; }
        const float la = la_s / 4194304.f;
        out[0] = (la + sb / 512.f + 0.5f * sc / 4096.f) / 3.f;
    }
}

extern "C" void kernel_launch(void* const* d_in, const int* in_sizes, int n_in,
                              void* d_out, int out_size, void* d_ws, size_t ws_size,
                              hipStream_t stream) {
    const float* theta0   = (const float*)d_in[0];   // [8192,4096]
    const float* theta1   = (const float*)d_in[1];   // [4096,2048]
    const float* obs0     = (const float*)d_in[2];   // [1024,4096]
    const float* obs1     = (const float*)d_in[3];   // [512]
    const float* obs2     = (const float*)d_in[4];   // [4096]
    const int*   idx0     = (const int*)d_in[5];     // [8192]
    const float* mapping1 = (const float*)d_in[6];   // [512,4096]
    float* out = (float*)d_out;

    char* ws = (char*)d_ws;
    float* lossC    = (float*)(ws + 0);        // 1 float
    int*   ticket   = (int*)(ws + 16);
    float* lossApart= (float*)(ws + 64);       // 64 floats, ends 320
    float* m1part   = (float*)(ws + 1024);     // 8*512 floats, ends 17408
    int*   counts   = (int*)(ws + 17408);      // 1024 ints, ends 21504
    float* p2fb     = (float*)(ws + 21504);    // 4096 floats, ends 37888
    float* s0       = (float*)(ws + 65536);    // 16 MB, ends 16842752
    int*   rowlist  = (int*)(ws + 16842752);   // 1024*64 ints, ends 17104896

    const size_t NEED_S0  = 16842752;
    const size_t NEED_ALL = 17104896;
    const bool haveS0  = ws_size >= NEED_S0;
    const bool haveCSR = ws_size >= NEED_ALL;

    hipMemsetAsync(ws, 0, 37888, stream);  // lossC + ticket + lossApart + m1part + counts + p2fb

    if (haveCSR) PREP<<<8, 1024, 0, stream>>>(idx0, counts, rowlist);

    MEGA<<<1280, 256, 0, stream>>>((const float4*)theta0, (const float4*)obs0, idx0,
                                   (const float4*)theta1, (const float4*)mapping1,
                                   haveS0 ? (float4*)s0 : nullptr, p2fb,
                                   lossApart, m1part,
                                   haveCSR ? counts : nullptr,
                                   haveCSR ? rowlist : nullptr);

    if (haveS0) {
        K3F<<<64, 1024, 0, stream>>>(s0, obs2, lossApart, lossC, ticket,
                                     m1part, obs1, out);
    } else {
        FINFB<<<1, 512, 0, stream>>>(m1part, obs1, lossApart, p2fb, obs2, out);
    }
}

// Round 8
// 250.045 us; speedup vs baseline: 1.1539x; 1.0102x over previous
//
#include <hip/hip_runtime.h>

typedef float vf4 __attribute__((ext_vector_type(4)));

__device__ __forceinline__ float4 ntload4(const float4* p) {
    vf4 v = __builtin_nontemporal_load((const vf4*)p);
    float4 r; r.x = v.x; r.y = v.y; r.z = v.z; r.w = v.w;
    return r;
}

__device__ __forceinline__ float4 exp4(float4 v) {
    float4 r;
    r.x = __expf(v.x); r.y = __expf(v.y); r.z = __expf(v.z); r.w = __expf(v.w);
    return r;
}

__device__ __forceinline__ void acc4(float4& a, float4 e) {
    a.x += e.x; a.y += e.y; a.z += e.z; a.w += e.w;
}

__device__ __forceinline__ float wave_reduce(float v) {
    #pragma unroll
    for (int off = 32; off > 0; off >>= 1) v += __shfl_down(v, off, 64);
    return v;
}

// ================= PREP: build group->rows CSR (counts pre-zeroed by memset) ================
// grid = 8, block = 1024
__global__ __launch_bounds__(1024) void PREP(const int* __restrict__ idx,
                                             int* __restrict__ counts,
                                             int* __restrict__ rowlist) {
    const int j = blockIdx.x * 1024 + threadIdx.x;   // 0..8191
    const int g = idx[j];
    const int p = atomicAdd(&counts[g], 1);
    if (p < 64) rowlist[(g << 6) + p] = j;
}

// ================= MEGA: blocks 0..255 theta1 path; blocks 256..1279 theta0 full-row groups =
// block = 256. Seg path: one block per group; full 16 KB rows; SOFTWARE-PIPELINED
// row-pair double-buffer (banks A/B of 8 nt-loads each) so vmcnt never drains mid-loop.
__global__ __launch_bounds__(256) void MEGA(const float4* __restrict__ theta0,
                                            const float4* __restrict__ obs0,
                                            const int* __restrict__ idx,
                                            const float4* __restrict__ theta1,
                                            const float4* __restrict__ mapping1,
                                            float4* __restrict__ s0,     // nullptr => p2fb atomics
                                            float* __restrict__ p2fb,
                                            float* __restrict__ lossApart, // [64] spread partials
                                            float* __restrict__ m1part,  // [8][512]
                                            const int* __restrict__ counts,   // may be null
                                            const int* __restrict__ rowlist)  // may be null
{
    __shared__ int rows_lds[64];
    __shared__ float p1s[16];

    const int t = threadIdx.x, lane = t & 63, wave = t >> 6;

    if (blockIdx.x < 256) {
        // ---- theta1: 16 row-sums of exp (nt loads), then mapping1 slice -> m1part ----
        const int b2 = blockIdx.x;
        #pragma unroll
        for (int rr = 0; rr < 4; ++rr) {
            const int lr = wave * 4 + rr;        // 0..15
            const float4* rp = theta1 + (size_t)(b2 * 16 + lr) * 512;
            float a = 0.f;
            #pragma unroll
            for (int i = 0; i < 8; ++i) {
                const float4 x = ntload4(rp + lane + i * 64);
                a += __expf(x.x) + __expf(x.y) + __expf(x.z) + __expf(x.w);
            }
            a = wave_reduce(a);
            if (lane == 0) p1s[lr] = a;
        }
        __syncthreads();
        float* mdst = m1part + (b2 & 7) * 512;
        #pragma unroll
        for (int rr = 0; rr < 2; ++rr) {
            const int r = t * 2 + rr;            // 0..511
            const float4* mp = mapping1 + (size_t)r * 1024 + b2 * 4;
            float s = 0.f;
            #pragma unroll
            for (int j = 0; j < 4; ++j) {
                const float4 m = ntload4(mp + j);
                s += m.x * p1s[j*4+0] + m.y * p1s[j*4+1]
                   + m.z * p1s[j*4+2] + m.w * p1s[j*4+3];
            }
            atomicAdd(&mdst[r], s);
        }
        return;
    }

    // ---- theta0 segment path: one block per group, full 16 KB rows, pipelined ----
    const int g = blockIdx.x - 256;

    const float4* base = theta0 + t;
    const size_t  o    = (size_t)g * 1024 + t;
    const float4  obA  = ntload4(obs0 + o);          // oldest in queue, consumed last
    const float4  obB  = ntload4(obs0 + o + 256);
    const float4  obC  = ntload4(obs0 + o + 512);
    const float4  obD  = ntload4(obs0 + o + 768);

    float4 aA = {0,0,0,0}, aB = {0,0,0,0}, aC = {0,0,0,0}, aD = {0,0,0,0};

    // bank registers: A = rows (s, s+1), B = rows (s+2, s+3)
    float4 A00, A01, A02, A03, A10, A11, A12, A13;
    float4 B00, B01, B02, B03, B10, B11, B12, B13;

#define LOADP(X00,X01,X02,X03,X10,X11,X12,X13, S) { \
    const float4* _p0 = base + (size_t)rows_lds[(S)]     * 1024; \
    const float4* _p1 = base + (size_t)rows_lds[(S) + 1] * 1024; \
    X00 = ntload4(_p0);       X01 = ntload4(_p0 + 256); \
    X02 = ntload4(_p0 + 512); X03 = ntload4(_p0 + 768); \
    X10 = ntload4(_p1);       X11 = ntload4(_p1 + 256); \
    X12 = ntload4(_p1 + 512); X13 = ntload4(_p1 + 768); }

#define CONSP(X00,X01,X02,X03,X10,X11,X12,X13) { \
    acc4(aA, exp4(X00)); acc4(aB, exp4(X01)); \
    acc4(aC, exp4(X02)); acc4(aD, exp4(X03)); \
    acc4(aA, exp4(X10)); acc4(aB, exp4(X11)); \
    acc4(aC, exp4(X12)); acc4(aD, exp4(X13)); }

    if (counts) {
        const int n = counts[g];                 // block-uniform
        if (n <= 64) {
            if (t < 64) rows_lds[t] = rowlist[(g << 6) + t];
            __syncthreads();

            const int even = n & ~1;
            int s = 0;
            if (even >= 2) LOADP(A00,A01,A02,A03,A10,A11,A12,A13, 0);
            while (s + 4 <= even) {
                LOADP(B00,B01,B02,B03,B10,B11,B12,B13, s + 2);
                CONSP(A00,A01,A02,A03,A10,A11,A12,A13);          // B stays outstanding
                if (s + 4 < even) LOADP(A00,A01,A02,A03,A10,A11,A12,A13, s + 4);
                CONSP(B00,B01,B02,B03,B10,B11,B12,B13);          // A stays outstanding
                s += 4;
            }
            if (s + 2 <= even) {                 // odd number of pairs: one bank left
                CONSP(A00,A01,A02,A03,A10,A11,A12,A13);
                s += 2;
            }
            if (n & 1) {                         // odd tail row
                const float4* p0 = base + (size_t)rows_lds[n - 1] * 1024;
                const float4 x0 = ntload4(p0),       x1 = ntload4(p0 + 256);
                const float4 x2 = ntload4(p0 + 512), x3 = ntload4(p0 + 768);
                acc4(aA, exp4(x0)); acc4(aB, exp4(x1));
                acc4(aC, exp4(x2)); acc4(aD, exp4(x3));
            }
        } else {
            // CSR overflow (n > 64): uniform scan-gather
            for (int j = 0; j < 8192; ++j)
                if (idx[j] == g) {
                    const float4* p = base + (size_t)j * 1024;
                    acc4(aA, exp4(ntload4(p)));
                    acc4(aB, exp4(ntload4(p + 256)));
                    acc4(aC, exp4(ntload4(p + 512)));
                    acc4(aD, exp4(ntload4(p + 768)));
                }
        }
    } else {
        // no-CSR fallback: uniform scan-gather (correctness path)
        for (int j = 0; j < 8192; ++j)
            if (idx[j] == g) {
                const float4* p = base + (size_t)j * 1024;
                acc4(aA, exp4(ntload4(p)));
                acc4(aB, exp4(ntload4(p + 256)));
                acc4(aC, exp4(ntload4(p + 512)));
                acc4(aD, exp4(ntload4(p + 768)));
            }
    }
#undef LOADP
#undef CONSP

    if (s0) {
        s0[o]       = aA;
        s0[o + 256] = aB;
        s0[o + 512] = aC;
        s0[o + 768] = aD;
    } else {
        #pragma unroll
        for (int k = 0; k < 4; ++k) {
            const float4 v = (k == 0) ? aA : (k == 1) ? aB : (k == 2) ? aC : aD;
            const int cc = (t + k * 256) * 4;
            atomicAdd(&p2fb[cc + 0], v.x); atomicAdd(&p2fb[cc + 1], v.y);
            atomicAdd(&p2fb[cc + 2], v.z); atomicAdd(&p2fb[cc + 3], v.w);
        }
    }

    const float dx0 = obA.x - aA.x, dy0 = obA.y - aA.y, dz0 = obA.z - aA.z, dw0 = obA.w - aA.w;
    const float dx1 = obB.x - aB.x, dy1 = obB.y - aB.y, dz1 = obB.z - aB.z, dw1 = obB.w - aB.w;
    const float dx2 = obC.x - aC.x, dy2 = obC.y - aC.y, dz2 = obC.z - aC.z, dw2 = obC.w - aC.w;
    const float dx3 = obD.x - aD.x, dy3 = obD.y - aD.y, dz3 = obD.z - aD.z, dw3 = obD.w - aD.w;
    float l = dx0*dx0 + dy0*dy0 + dz0*dz0 + dw0*dw0
            + dx1*dx1 + dy1*dy1 + dz1*dz1 + dw1*dw1
            + dx2*dx2 + dy2*dy2 + dz2*dz2 + dw2*dw2
            + dx3*dx3 + dy3*dy3 + dz3*dz3 + dw3*dw3;
    l = wave_reduce(l);
    if (lane == 0) atomicAdd(&lossApart[g & 63], l);   // spread partials
}

// ================= K3F: column sums of s0 + loss_c; last block does loss_b + combine =========
// grid = 64, block = 1024
__global__ __launch_bounds__(1024) void K3F(const float* __restrict__ s0,
                                            const float* __restrict__ obs2,
                                            const float* __restrict__ lossApart,
                                            float* __restrict__ lossC,
                                            int* __restrict__ ticket,
                                            const float* __restrict__ m1part,
                                            const float* __restrict__ obs1,
                                            float* __restrict__ out) {
    __shared__ float part[16][64];
    __shared__ int isLast;
    const int tid = threadIdx.x, lane = tid & 63, wave = tid >> 6;
    const int col = blockIdx.x * 64 + lane;
    const float* p = s0 + (size_t)wave * 4096 + col;
    float a = 0.f;
    #pragma unroll 4
    for (int g = 0; g < 64; ++g) a += p[(size_t)g * 16 * 4096];
    part[wave][lane] = a;
    __syncthreads();
    if (wave == 0) {
        float s = 0.f;
        #pragma unroll
        for (int k = 0; k < 16; ++k) s += part[k][lane];
        const float d = obs2[col] - s;
        const float l = wave_reduce(d * d);
        if (lane == 0) {
            atomicAdd(lossC, l);
            __threadfence();
        }
    }
    __syncthreads();
    if (tid == 0) isLast = (atomicAdd(ticket, 1) == 63) ? 1 : 0;
    __syncthreads();
    if (!isLast) return;

    // ---- final: loss_b + lossA partials + combine ----
    __shared__ float wb[16];
    __shared__ float la_s;
    float lb = 0.f;
    if (tid < 512) {
        float m = 0.f;
        #pragma unroll
        for (int k = 0; k < 8; ++k) m += m1part[k * 512 + tid];
        const float d = obs1[tid] - m;
        lb = d * d;
    }
    lb = wave_reduce(lb);
    if (lane == 0) wb[wave] = lb;
    if (wave == 0) {
        float la = (lane < 64) ? lossApart[lane] : 0.f;
        la = wave_reduce(la);
        if (lane == 0) la_s = la;
    }
    __syncthreads();
    if (tid == 0) {
        float sb = 0.f;
        #pragma unroll
        for (int i = 0; i < 16; ++i) sb += wb[i];
        const float sc = atomicAdd(lossC, 0.f);   // coherent read
        const float la = la_s / 4194304.f;
        out[0] = (la + sb / 512.f + 0.5f * sc / 4096.f) / 3.f;
    }
}

// ================= FINFB: fallback final (loss_b + loss_c from p2fb + combine) ==============
// grid = 1, block = 512
__global__ __launch_bounds__(512) void FINFB(const float* __restrict__ m1part,
                                             const float* __restrict__ obs1,
                                             const float* __restrict__ lossApart,
                                             const float* __restrict__ p2,
                                             const float* __restrict__ obs2,
                                             float* __restrict__ out) {
    __shared__ float wb[8];
    __shared__ float wc[8];
    __shared__ float la_s;
    const int t = threadIdx.x, lane = t & 63, wave = t >> 6;
    float m = 0.f;
    #pragma unroll
    for (int k = 0; k < 8; ++k) m += m1part[k * 512 + t];
    const float d = obs1[t] - m;
    const float lb = wave_reduce(d * d);
    float acc = 0.f;
    #pragma unroll
    for (int i = 0; i < 8; ++i) {
        const int c = t + i * 512;
        const float dd = obs2[c] - p2[c];
        acc += dd * dd;
    }
    const float lc = wave_reduce(acc);
    if (lane == 0) { wb[wave] = lb; wc[wave] = lc; }
    if (wave == 0) {
        float la = (lane < 64) ? lossApart[lane] : 0.f;
        la = wave_reduce(la);
        if (lane == 0) la_s = la;
    }
    __syncthreads();
    if (t == 0) {
        float sb = 0.f, sc = 0.f;
        #pragma unroll
        for (int i = 0; i < 8; ++i) { sb += wb[i]; sc += wc[i]; }
        const float la = la_s / 4194304.f;
        out[0] = (la + sb / 512.f + 0.5f * sc / 4096.f) / 3.f;
    }
}

extern "C" void kernel_launch(void* const* d_in, const int* in_sizes, int n_in,
                              void* d_out, int out_size, void* d_ws, size_t ws_size,
                              hipStream_t stream) {
    const float* theta0   = (const float*)d_in[0];   // [8192,4096]
    const float* theta1   = (const float*)d_in[1];   // [4096,2048]
    const float* obs0     = (const float*)d_in[2];   // [1024,4096]
    const float* obs1     = (const float*)d_in[3];   // [512]
    const float* obs2     = (const float*)d_in[4];   // [4096]
    const int*   idx0     = (const int*)d_in[5];     // [8192]
    const float* mapping1 = (const float*)d_in[6];   // [512,4096]
    float* out = (float*)d_out;

    char* ws = (char*)d_ws;
    float* lossC    = (float*)(ws + 0);        // 1 float
    int*   ticket   = (int*)(ws + 16);
    float* lossApart= (float*)(ws + 64);       // 64 floats, ends 320
    float* m1part   = (float*)(ws + 1024);     // 8*512 floats, ends 17408
    int*   counts   = (int*)(ws + 17408);      // 1024 ints, ends 21504
    float* p2fb     = (float*)(ws + 21504);    // 4096 floats, ends 37888
    float* s0       = (float*)(ws + 65536);    // 16 MB, ends 16842752
    int*   rowlist  = (int*)(ws + 16842752);   // 1024*64 ints, ends 17104896

    const size_t NEED_S0  = 16842752;
    const size_t NEED_ALL = 17104896;
    const bool haveS0  = ws_size >= NEED_S0;
    const bool haveCSR = ws_size >= NEED_ALL;

    hipMemsetAsync(ws, 0, 37888, stream);  // lossC + ticket + lossApart + m1part + counts + p2fb

    if (haveCSR) PREP<<<8, 1024, 0, stream>>>(idx0, counts, rowlist);

    MEGA<<<1280, 256, 0, stream>>>((const float4*)theta0, (const float4*)obs0, idx0,
                                   (const float4*)theta1, (const float4*)mapping1,
                                   haveS0 ? (float4*)s0 : nullptr, p2fb,
                                   lossApart, m1part,
                                   haveCSR ? counts : nullptr,
                                   haveCSR ? rowlist : nullptr);

    if (haveS0) {
        K3F<<<64, 1024, 0, stream>>>(s0, obs2, lossApart, lossC, ticket,
                                     m1part, obs1, out);
    } else {
        FINFB<<<1, 512, 0, stream>>>(m1part, obs1, lossApart, p2fb, obs2, out);
    }
}